// Round 9
// baseline (5980.001 us; speedup 1.0000x reference)
//
#include <hip/hip_runtime.h>
#include <cstdint>
#include <cstddef>

typedef __bf16 bf16;
typedef float f32x4 __attribute__((ext_vector_type(4)));
typedef bf16 bf16x8 __attribute__((ext_vector_type(8)));

#define AS1 __attribute__((address_space(1)))
#define AS3 __attribute__((address_space(3)))

__device__ __forceinline__ void gload_lds16(const void* g, void* l) {
  __builtin_amdgcn_global_load_lds((AS1 void*)g, (AS3 void*)l, 16, 0, 0);
}

#define FLAG_WORDS 1024
#define NTILE 16000u
#define RW 32000ull  // floats per logits row

__device__ __forceinline__ size_t LROW(int b, int t) {
  return ((size_t)b * 512 + (size_t)t) * RW;
}

// ---------------- init: combined biases + flags/queue ----------------
__global__ __launch_bounds__(256) void init_misc(
    const float* __restrict__ bih0, const float* __restrict__ bhh0,
    const float* __restrict__ bih1, const float* __restrict__ bhh1,
    float* __restrict__ bsum0, float* __restrict__ bsum1, unsigned* __restrict__ flags) {
  int i = blockIdx.x * 256 + threadIdx.x;
  if (i < 4096) {
    bsum0[i] = bih0[i] + bhh0[i];
    bsum1[i] = bih1[i] + bhh1[i];
  }
  if (i < FLAG_WORDS) flags[i] = 0u;
}

// ---------------- fused embed + GEMM0: gx = emb[x] @ Wih0^T + bsum0 ----------------
// C rows hosted in logits space: gx(t,b) -> C[LROW(b,t) + 0..4096)
__global__ __launch_bounds__(256) void gemm_emb(
    const int* __restrict__ x, const float* __restrict__ emb,
    const float* __restrict__ Wih0, const float* __restrict__ bsum0,
    float* __restrict__ C) {
  __shared__ bf16 aL[2][4096];
  __shared__ bf16 bL[2][4096];
  const int tid = threadIdx.x;
  const int l = tid & 63, w = tid >> 6;
  const int bm = blockIdx.x & 63;  // 64 row tiles (M=8192)
  const int bn = blockIdx.x >> 6;  // 32 col tiles (N=4096)
  const int wr = (w >> 1) << 6, wc = (w & 1) << 6;
  const int r16 = l & 15, kq = l >> 4;

  f32x4 acc[4][4];
  for (int m = 0; m < 4; ++m)
    for (int n = 0; n < 4; ++n) acc[m][n] = (f32x4){0.f, 0.f, 0.f, 0.f};

  auto stage = [&](int kt, int buf) {
    for (int i = 0; i < 2; ++i) {
      int lin = tid + (i << 8);
      int r = lin >> 2, c = lin & 3;
      int rg = (bm << 7) + r;
      int tok = x[((rg & 15) << 9) + (rg >> 4)];  // x[b*512 + t]
      const float* sa = emb + ((size_t)tok << 10) + (kt << 5) + (c << 3);
      f32x4 a0 = *(const f32x4*)sa;
      f32x4 a1 = *(const f32x4*)(sa + 4);
      bf16x8 oa;
      for (int j = 0; j < 4; ++j) { oa[j] = (bf16)a0[j]; oa[j + 4] = (bf16)a1[j]; }
      *(bf16x8*)&aL[buf][(r << 5) + ((c ^ (r & 3)) << 3)] = oa;
      const float* sb = Wih0 + (size_t)((bn << 7) + r) * 1024 + (kt << 5) + (c << 3);
      f32x4 b0 = *(const f32x4*)sb;
      f32x4 b1 = *(const f32x4*)(sb + 4);
      bf16x8 ob;
      for (int j = 0; j < 4; ++j) { ob[j] = (bf16)b0[j]; ob[j + 4] = (bf16)b1[j]; }
      *(bf16x8*)&bL[buf][(r << 5) + ((c ^ (r & 3)) << 3)] = ob;
    }
  };
  stage(0, 0);
  __syncthreads();
  for (int kt = 0; kt < 32; ++kt) {
    int cur = kt & 1;
    if (kt + 1 < 32) stage(kt + 1, cur ^ 1);  // other buffer: no hazard until sync
    bf16x8 af[4], bfr[4];
    for (int m = 0; m < 4; ++m) {
      int row = wr + (m << 4) + r16;
      int ch = kq ^ (row & 3);
      af[m] = *(const bf16x8*)&aL[cur][(row << 5) + (ch << 3)];
    }
    for (int n = 0; n < 4; ++n) {
      int row = wc + (n << 4) + r16;
      int ch = kq ^ (row & 3);
      bfr[n] = *(const bf16x8*)&bL[cur][(row << 5) + (ch << 3)];
    }
    for (int m = 0; m < 4; ++m)
      for (int n = 0; n < 4; ++n)
        acc[m][n] = __builtin_amdgcn_mfma_f32_16x16x32_bf16(af[m], bfr[n], acc[m][n], 0, 0, 0);
    __syncthreads();
  }
  float bvv[4];
  for (int n = 0; n < 4; ++n) bvv[n] = bsum0[(bn << 7) + wc + (n << 4) + r16];
  for (int m = 0; m < 4; ++m) {
    int Rbase = (bm << 7) + wr + (m << 4) + (kq << 2);
    for (int r = 0; r < 4; ++r) {
      int R = Rbase + r;
      int tt = R >> 4, bb = R & 15;
      size_t rowoff = LROW(bb, tt);
      for (int n = 0; n < 4; ++n)
        C[rowoff + (bn << 7) + wc + (n << 4) + r16] = acc[m][n][r] + bvv[n];
    }
  }
}

// ---------------- mega kernel: recurrence (L0,B,L1) + overlapped projection ----------------
// bid 0..63 L0 | 64..127 B (gx1 = Wih1*h0+b) | 128..191 L1 | 192..255 projection.
// Scratch hosted in dead-gated logits rows (see round-8 proof):
//   gx(t,b) = C[LROW(b,t)+0..4096) ; hs0t[t] = C[LROW(0,t)+4096..12288) ;
//   hs1t[t] = C[LROW(0,t)+12288..20480) ; gx1[t] split in rows (1..3,t)+4096...
// Projection: super-row ordering (rc = 8s+dr, cc-major within) so each Wout
// slice is reused across 8 row-chunks while L2-resident; logits stored with nt
// so the streaming output can't evict Wout/hs1rm from L2/L3.
__global__ __launch_bounds__(256, 1) void lstm_mega(
    const float* __restrict__ Whh0, const float* __restrict__ Wih1,
    const float* __restrict__ Whh1, const float* __restrict__ bsum1,
    bf16* __restrict__ hs1rm, const float* __restrict__ Wout,
    const float* __restrict__ bout, float* __restrict__ C,
    unsigned* __restrict__ flags) {
  __shared__ bf16 wlds[4][16 * 1024];   // 128 KB weights (recurrence) / proj LDS alias
  __shared__ unsigned short hb[4][64];  // per-wave transpose bounce
  __shared__ unsigned tokv[3][4];       // poll tokens per flag-group
  __shared__ unsigned qsh;
  const int tid = threadIdx.x, l = tid & 63, w = tid >> 6;
  const int bid = blockIdx.x;
  const int r16 = l & 15, kq = l >> 4;
  unsigned* const fL0 = flags;
  unsigned* const fB = flags + 256;
  unsigned* const fL1 = flags + 512;
  unsigned* const qctr = flags + 768;
  const int typ = bid >> 6;
  const int lb = bid & 63;
  const int widx = lb * 4 + w;
  const int colbase = lb * 16 + w * 4;
  const int T = 512;

  if (typ < 3) {  // stage wave's 16 weight rows (4 cols x 4 gates), swizzled
    const float* Wsrc = (typ == 0) ? Whh0 : ((typ == 1) ? Wih1 : Whh1);
    for (int it = 0; it < 32; ++it) {
      int lin = it * 64 + l;
      int row = lin >> 7, cs = lin & 127, c = cs ^ (row & 7);
      const float* s = Wsrc + (size_t)((row >> 2) * 1024 + colbase + (row & 3)) * 1024 + c * 8;
      f32x4 v0 = *(const f32x4*)s;
      f32x4 v1 = *(const f32x4*)(s + 4);
      bf16x8 o;
      for (int j = 0; j < 4; ++j) { o[j] = (bf16)v0[j]; o[j + 4] = (bf16)v1[j]; }
      *(bf16x8*)&wlds[w][row * 1024 + cs * 8] = o;
    }
  }
  if (tid < 12) ((unsigned*)tokv)[tid] = 0;
  __syncthreads();

  auto pollq = [&](int gid, unsigned* arr, unsigned tgt, int slp) {
    unsigned* q = arr + w * 64 + (l & 15) * 4;
    for (;;) {
      unsigned a0 = __hip_atomic_load(q + 0, __ATOMIC_RELAXED, __HIP_MEMORY_SCOPE_AGENT);
      unsigned a1 = __hip_atomic_load(q + 1, __ATOMIC_RELAXED, __HIP_MEMORY_SCOPE_AGENT);
      unsigned a2 = __hip_atomic_load(q + 2, __ATOMIC_RELAXED, __HIP_MEMORY_SCOPE_AGENT);
      unsigned a3 = __hip_atomic_load(q + 3, __ATOMIC_RELAXED, __HIP_MEMORY_SCOPE_AGENT);
      if (__all(a0 >= tgt && a1 >= tgt && a2 >= tgt && a3 >= tgt)) break;
      if (slp == 2) __builtin_amdgcn_s_sleep(2);
      else __builtin_amdgcn_s_sleep(8);
    }
    volatile unsigned* tk = tokv[gid];
    if (l == 0 && tk[w] < tgt) tk[w] = tgt;
    while (tk[0] < tgt || tk[1] < tgt || tk[2] < tgt || tk[3] < tgt) {
    }
    asm volatile("" ::: "memory");
  };
  auto poll1 = [&](unsigned* p, unsigned tgt) {
    while (__hip_atomic_load(p, __ATOMIC_RELAXED, __HIP_MEMORY_SCOPE_AGENT) < tgt)
      __builtin_amdgcn_s_sleep(2);
    asm volatile("" ::: "memory");
  };
  auto chain = [&](const bf16* plane) -> f32x4 {
    f32x4 acc = (f32x4){0.f, 0.f, 0.f, 0.f};
    const char* hp = (const char*)plane;
#pragma unroll 8
    for (int kk = 0; kk < 32; ++kk) {
      int tl = kk * 8 + kq * 2;
      unsigned long long lo = *(const unsigned long long*)(hp + tl * 128 + r16 * 8);
      unsigned long long hi = *(const unsigned long long*)(hp + tl * 128 + 128 + r16 * 8);
      union { struct { unsigned long long a, b; } u; bf16x8 v; } A;
      A.u.a = lo;
      A.u.b = hi;
      bf16x8 Bf = *(const bf16x8*)&wlds[w][r16 * 1024 + (((kk * 4 + kq) ^ (r16 & 7)) << 3)];
      acc = __builtin_amdgcn_mfma_f32_16x16x32_bf16(A.v, Bf, acc, 0, 0, 0);
    }
    return acc;
  };
  auto hs0p = [&](int t) { return (bf16*)(C + LROW(0, t) + 4096); };
  auto hs1p = [&](int t) { return (bf16*)(C + LROW(0, t) + 12288); };
  auto gx1p = [&](int t, unsigned idx) -> float* {
    if (idx < 27904u) return C + LROW(1, t) + 4096 + idx;
    if (idx < 55808u) return C + LROW(2, t) + 4096 + (idx - 27904u);
    return C + LROW(3, t) + 4096 + (idx - 55808u);
  };
  const int gcol = (r16 >> 2) * 1024 + colbase + (r16 & 3);
  const int b0s = (r16 >> 2) & 1, b1s = (r16 >> 3) & 1;

  auto gates = [&](f32x4 acc, float* cst, float* hv) {
    for (int r = 0; r < 4; ++r) {
      float own = acc[r];
      float p4 = __shfl_xor(own, 4, 64);
      float ev = b0s ? p4 : own;
      float ov = b0s ? own : p4;
      float ev8 = __shfl_xor(ev, 8, 64);
      float ov8 = __shfl_xor(ov, 8, 64);
      float xi = b1s ? ev8 : ev;
      float xf = b1s ? ov8 : ov;
      float xg = b1s ? ev : ev8;
      float xo = b1s ? ov : ov8;
      float ig = 1.f / (1.f + __expf(-xi));
      float fg = 1.f / (1.f + __expf(-xf));
      float eg = __expf(2.f * xg);
      float gv = 1.f - 2.f / (eg + 1.f);
      float og = 1.f / (1.f + __expf(-xo));
      cst[r] = fg * cst[r] + ig * gv;
      float ec = __expf(2.f * cst[r]);
      float th = 1.f - 2.f / (ec + 1.f);
      hv[r] = og * th;
    }
  };
  auto transpose_store = [&](float* hv, char* dstbase) -> unsigned long long {
    if (r16 < 4) {
      volatile unsigned short* hbp = hb[w];
      for (int r = 0; r < 4; ++r) {
        bf16 hbv = (bf16)hv[r];
        hbp[(kq * 4 + r) * 4 + r16] = __builtin_bit_cast(unsigned short, hbv);
      }
    }
    unsigned long long rowv = 0;
    if (l < 16) {
      rowv = *(volatile unsigned long long*)&hb[w][l * 4];
      char* dst = dstbase + widx * 128 + l * 8;
      asm volatile("global_store_dwordx2 %0, %1, off sc0 sc1" ::"v"(dst), "v"(rowv) : "memory");
    }
    return rowv;
  };

  if (typ == 0) {  // ---------- L0 recurrence ----------
    float cst[4] = {0.f, 0.f, 0.f, 0.f};
    unsigned* const myflag = fL0 + widx;
    for (int t = 0; t < T; ++t) {
      float gxv[4];
      for (int r = 0; r < 4; ++r) gxv[r] = C[LROW(kq * 4 + r, t) + gcol];  // prefetch
      if (t > 0) pollq(0, fL0, (unsigned)t, 2);
      f32x4 acc = (f32x4){0.f, 0.f, 0.f, 0.f};
      if (t > 0) acc = chain(hs0p(t - 1));
      for (int r = 0; r < 4; ++r) acc[r] += gxv[r];
      float hv[4];
      gates(acc, cst, hv);
      transpose_store(hv, (char*)hs0p(t));
      asm volatile("s_waitcnt vmcnt(0)" ::: "memory");
      if (l == 0)
        __hip_atomic_store(myflag, (unsigned)(t + 1), __ATOMIC_RELAXED, __HIP_MEMORY_SCOPE_AGENT);
    }
  } else if (typ == 1) {  // ---------- B: gx1[t] = Wih1*h0[t] + bsum1 ----------
    const float bsv = bsum1[gcol];
    unsigned* const myflag = fB + widx;
    for (int t = 0; t < T; ++t) {
      pollq(0, fL0, (unsigned)(t + 1), 2);
      f32x4 acc = chain(hs0p(t));
      for (int r = 0; r < 4; ++r) acc[r] += bsv;
      float* dst = gx1p(t, (unsigned)(widx * 256 + r16 * 16 + kq * 4));
      asm volatile("global_store_dwordx4 %0, %1, off sc0 sc1" ::"v"(dst), "v"(acc) : "memory");
      asm volatile("s_waitcnt vmcnt(0)" ::: "memory");
      if (l == 0)
        __hip_atomic_store(myflag, (unsigned)(t + 1), __ATOMIC_RELAXED, __HIP_MEMORY_SCOPE_AGENT);
    }
  } else if (typ == 2) {  // ---------- L1 recurrence ----------
    float cst[4] = {0.f, 0.f, 0.f, 0.f};
    unsigned* const myflag = fL1 + widx;
    unsigned* const bpartner = fB + widx;
    for (int t = 0; t < T; ++t) {
      poll1(bpartner, (unsigned)(t + 1));
      if (t > 0) pollq(2, fL1, (unsigned)t, 2);
      f32x4 acc = (f32x4){0.f, 0.f, 0.f, 0.f};
      if (t > 0) acc = chain(hs1p(t - 1));
      const float* gp = gx1p(t, (unsigned)(widx * 256 + r16 * 16 + kq * 4));
      f32x4 g1;
      asm volatile("global_load_dwordx4 %0, %1, off sc0 sc1\ns_waitcnt vmcnt(0)"
                   : "=v"(g1) : "v"(gp) : "memory");
      for (int r = 0; r < 4; ++r) acc[r] += g1[r];
      float hv[4];
      gates(acc, cst, hv);
      unsigned long long rowv = transpose_store(hv, (char*)hs1p(t));
      if (l < 16) {  // row-major mirror for projection, pre-drain, write-through
        char* dst = (char*)hs1rm + ((size_t)(t * 16 + l) * 1024 + colbase) * 2;
        asm volatile("global_store_dwordx2 %0, %1, off sc0 sc1" ::"v"(dst), "v"(rowv) : "memory");
      }
      asm volatile("s_waitcnt vmcnt(0)" ::: "memory");
      if (l == 0)
        __hip_atomic_store(myflag, (unsigned)(t + 1), __ATOMIC_RELAXED, __HIP_MEMORY_SCOPE_AGENT);
    }
  }

  // ---------- projection: queue-fed, flag-gated, super-row ordered ----------
  // tau -> s = tau/2000 (8 rc), cc = (tau%2000)/8, rc = 8s + tau%8.
  bf16* const paL = &wlds[0][0];     // [2][4096]
  bf16* const pbL = &wlds[0][8192];  // [2][4096]
  const int wr = (w >> 1) << 6, wc2 = (w & 1) << 6;
  for (;;) {
    __syncthreads();
    if (tid == 0) qsh = atomicAdd(qctr, 1u);
    __syncthreads();
    unsigned tau = qsh;
    if (tau >= NTILE) break;
    unsigned sr = tau / 2000u;
    unsigned rem = tau - sr * 2000u;
    int cc = (int)(rem >> 3);
    int rc = (int)(sr * 8u + (rem & 7u));
    unsigned g0 = (unsigned)(8 * rc + 9);
    if (g0 > 512u) g0 = 512u;
    pollq(0, fL0, g0, 8);
    pollq(2, fL1, g0, 8);
    __syncthreads();
    f32x4 acc[4][4];
    for (int m = 0; m < 4; ++m)
      for (int n = 0; n < 4; ++n) acc[m][n] = (f32x4){0.f, 0.f, 0.f, 0.f};
    // prologue kt=0
    for (int i = 0; i < 2; ++i) {
      int lin = tid + (i << 8);
      int r = lin >> 2, s2 = lin & 3, c = s2 ^ (r & 3);
      gload_lds16(hs1rm + (size_t)(rc * 128 + r) * 1024 + (c << 3), &paL[lin << 3]);
    }
    for (int i = 0; i < 2; ++i) {
      int lin = tid + (i << 8);
      int r = lin >> 2, c = lin & 3;
      const float* src = Wout + (size_t)(cc * 128 + r) * 1024 + (c << 3);
      f32x4 v0 = *(const f32x4*)src;
      f32x4 v1 = *(const f32x4*)(src + 4);
      bf16x8 o;
      for (int j = 0; j < 4; ++j) { o[j] = (bf16)v0[j]; o[j + 4] = (bf16)v1[j]; }
      *(bf16x8*)&pbL[(r << 5) + ((c ^ (r & 3)) << 3)] = o;
    }
    __syncthreads();
    for (int kt = 0; kt < 32; ++kt) {
      const int cur = kt & 1;
      const bool pf = (kt + 1 < 32);
      f32x4 bv0[2], bv1[2];
      int br_[2], bs_[2];
      if (pf) {
        for (int i = 0; i < 2; ++i) {
          int lin = tid + (i << 8);
          int r = lin >> 2, s2 = lin & 3, c = s2 ^ (r & 3);
          gload_lds16(hs1rm + (size_t)(rc * 128 + r) * 1024 + ((kt + 1) << 5) + (c << 3),
                      &paL[(cur ^ 1) * 4096 + (lin << 3)]);
        }
        for (int i = 0; i < 2; ++i) {
          int lin = tid + (i << 8);
          int r = lin >> 2, c = lin & 3;
          const float* src = Wout + (size_t)(cc * 128 + r) * 1024 + ((kt + 1) << 5) + (c << 3);
          bv0[i] = *(const f32x4*)src;
          bv1[i] = *(const f32x4*)(src + 4);
          br_[i] = r;
          bs_[i] = c ^ (r & 3);
        }
      }
      bf16x8 af[4], bfr[4];
      for (int m = 0; m < 4; ++m) {
        int row = wr + (m << 4) + r16;
        int ch = kq ^ (row & 3);
        af[m] = *(const bf16x8*)&paL[cur * 4096 + (row << 5) + (ch << 3)];
      }
      for (int n = 0; n < 4; ++n) {
        int row = wc2 + (n << 4) + r16;
        int ch = kq ^ (row & 3);
        bfr[n] = *(const bf16x8*)&pbL[cur * 4096 + (row << 5) + (ch << 3)];
      }
      for (int m = 0; m < 4; ++m)
        for (int n = 0; n < 4; ++n)
          acc[m][n] = __builtin_amdgcn_mfma_f32_16x16x32_bf16(af[m], bfr[n], acc[m][n], 0, 0, 0);
      if (pf) {
        for (int i = 0; i < 2; ++i) {
          bf16x8 o;
          for (int j = 0; j < 4; ++j) { o[j] = (bf16)bv0[i][j]; o[j + 4] = (bf16)bv1[i][j]; }
          *(bf16x8*)&pbL[(cur ^ 1) * 4096 + (br_[i] << 5) + (bs_[i] << 3)] = o;
        }
      }
      __syncthreads();
    }
    float bvv[4];
    for (int n = 0; n < 4; ++n) bvv[n] = bout[cc * 128 + wc2 + (n << 4) + r16];
    for (int m = 0; m < 4; ++m) {
      int Rbase = rc * 128 + wr + (m << 4) + (kq << 2);
      for (int r = 0; r < 4; ++r) {
        int R = Rbase + r;
        int tt = R >> 4, bb = R & 15;
        size_t rowoff = LROW(bb, tt);
        for (int n = 0; n < 4; ++n) {
          float v = acc[m][n][r] + bvv[n];
          float* cp = &C[rowoff + cc * 128 + wc2 + (n << 4) + r16];
          asm volatile("global_store_dword %0, %1, off nt" ::"v"(cp), "v"(v) : "memory");
        }
      }
    }
  }
}

extern "C" void kernel_launch(void* const* d_in, const int* in_sizes, int n_in,
                              void* d_out, int out_size, void* d_ws, size_t ws_size,
                              hipStream_t stream) {
  const int* x = (const int*)d_in[0];
  const float* emb = (const float*)d_in[1];
  const float* Wih0 = (const float*)d_in[2];
  const float* Whh0 = (const float*)d_in[3];
  const float* bih0 = (const float*)d_in[4];
  const float* bhh0 = (const float*)d_in[5];
  const float* Wih1 = (const float*)d_in[6];
  const float* Whh1 = (const float*)d_in[7];
  const float* bih1 = (const float*)d_in[8];
  const float* bhh1 = (const float*)d_in[9];
  const float* Wout = (const float*)d_in[10];
  const float* bout = (const float*)d_in[11];

  const int M = 8192;
  const size_t bfb = (size_t)M * 1024 * 2;  // 16 MiB

  char* p = (char*)d_ws;
  bf16* hs1rm = (bf16*)p;         p += bfb;
  float* bsum0 = (float*)p;       p += 4096 * 4;
  float* bsum1 = (float*)p;       p += 4096 * 4;
  unsigned* flags = (unsigned*)p; p += FLAG_WORDS * 4;
  (void)ws_size;

  float* C = (float*)d_out;

  init_misc<<<64, 256, 0, stream>>>(bih0, bhh0, bih1, bhh1, bsum0, bsum1, flags);
  gemm_emb<<<64 * 32, 256, 0, stream>>>(x, emb, Wih0, bsum0, C);
  lstm_mega<<<256, 256, 0, stream>>>(Whh0, Wih1, Whh1, bsum1, hs1rm, Wout, bout, C, flags);
}

// Round 10
// 5068.824 us; speedup vs baseline: 1.1798x; 1.1798x over previous
//
#include <hip/hip_runtime.h>
#include <cstdint>
#include <cstddef>

typedef __bf16 bf16;
typedef float f32x4 __attribute__((ext_vector_type(4)));
typedef bf16 bf16x8 __attribute__((ext_vector_type(8)));

#define AS1 __attribute__((address_space(1)))
#define AS3 __attribute__((address_space(3)))

__device__ __forceinline__ void gload_lds16(const void* g, void* l) {
  __builtin_amdgcn_global_load_lds((AS1 void*)g, (AS3 void*)l, 16, 0, 0);
}

#define RING 8
#define FLAG_WORDS 1024

// ---------------- init: combined biases + flags ----------------
__global__ __launch_bounds__(256) void init_misc(
    const float* __restrict__ bih0, const float* __restrict__ bhh0,
    const float* __restrict__ bih1, const float* __restrict__ bhh1,
    float* __restrict__ bsum0, float* __restrict__ bsum1, unsigned* __restrict__ flags) {
  int i = blockIdx.x * 256 + threadIdx.x;
  if (i < 4096) {
    bsum0[i] = bih0[i] + bhh0[i];
    bsum1[i] = bih1[i] + bhh1[i];
  }
  if (i < FLAG_WORDS) flags[i] = 0u;
}

// ---------------- Wout f32 -> bf16 (one pass, ws-resident) ----------------
__global__ __launch_bounds__(256) void wout_cvt(
    const float* __restrict__ W, bf16* __restrict__ o) {
  size_t i = ((size_t)blockIdx.x * 256 + threadIdx.x) * 8;
  f32x4 v0 = *(const f32x4*)(W + i);
  f32x4 v1 = *(const f32x4*)(W + i + 4);
  bf16x8 r;
  for (int j = 0; j < 4; ++j) { r[j] = (bf16)v0[j]; r[j + 4] = (bf16)v1[j]; }
  *(bf16x8*)(o + i) = r;
}

// ---------------- fused embed + GEMM0: gx = emb[x] @ Wih0^T + bsum0 ----------------
__global__ __launch_bounds__(256) void gemm_emb(
    const int* __restrict__ x, const float* __restrict__ emb,
    const float* __restrict__ Wih0, const float* __restrict__ bsum0,
    float* __restrict__ C) {
  __shared__ bf16 aL[2][4096];
  __shared__ bf16 bL[2][4096];
  const int tid = threadIdx.x;
  const int l = tid & 63, w = tid >> 6;
  const int bm = blockIdx.x & 63;  // 64 row tiles (M=8192)
  const int bn = blockIdx.x >> 6;  // 32 col tiles (N=4096)
  const int wr = (w >> 1) << 6, wc = (w & 1) << 6;
  const int r16 = l & 15, kq = l >> 4;

  f32x4 acc[4][4];
  for (int m = 0; m < 4; ++m)
    for (int n = 0; n < 4; ++n) acc[m][n] = (f32x4){0.f, 0.f, 0.f, 0.f};

  auto stage = [&](int kt, int buf) {
    for (int i = 0; i < 2; ++i) {
      int lin = tid + (i << 8);
      int r = lin >> 2, c = lin & 3;
      int rg = (bm << 7) + r;
      int tok = x[((rg & 15) << 9) + (rg >> 4)];  // x[b*512 + t]
      const float* sa = emb + ((size_t)tok << 10) + (kt << 5) + (c << 3);
      f32x4 a0 = *(const f32x4*)sa;
      f32x4 a1 = *(const f32x4*)(sa + 4);
      bf16x8 oa;
      for (int j = 0; j < 4; ++j) { oa[j] = (bf16)a0[j]; oa[j + 4] = (bf16)a1[j]; }
      *(bf16x8*)&aL[buf][(r << 5) + ((c ^ (r & 3)) << 3)] = oa;
      const float* sb = Wih0 + (size_t)((bn << 7) + r) * 1024 + (kt << 5) + (c << 3);
      f32x4 b0 = *(const f32x4*)sb;
      f32x4 b1 = *(const f32x4*)(sb + 4);
      bf16x8 ob;
      for (int j = 0; j < 4; ++j) { ob[j] = (bf16)b0[j]; ob[j + 4] = (bf16)b1[j]; }
      *(bf16x8*)&bL[buf][(r << 5) + ((c ^ (r & 3)) << 3)] = ob;
    }
  };
  stage(0, 0);
  __syncthreads();
  for (int kt = 0; kt < 32; ++kt) {
    int cur = kt & 1;
    if (kt + 1 < 32) stage(kt + 1, cur ^ 1);
    bf16x8 af[4], bfr[4];
    for (int m = 0; m < 4; ++m) {
      int row = wr + (m << 4) + r16;
      int ch = kq ^ (row & 3);
      af[m] = *(const bf16x8*)&aL[cur][(row << 5) + (ch << 3)];
    }
    for (int n = 0; n < 4; ++n) {
      int row = wc + (n << 4) + r16;
      int ch = kq ^ (row & 3);
      bfr[n] = *(const bf16x8*)&bL[cur][(row << 5) + (ch << 3)];
    }
    for (int m = 0; m < 4; ++m)
      for (int n = 0; n < 4; ++n)
        acc[m][n] = __builtin_amdgcn_mfma_f32_16x16x32_bf16(af[m], bfr[n], acc[m][n], 0, 0, 0);
    __syncthreads();
  }
  float bvv[4];
  for (int n = 0; n < 4; ++n) bvv[n] = bsum0[(bn << 7) + wc + (n << 4) + r16];
  for (int m = 0; m < 4; ++m) {
    int Rbase = (bm << 7) + wr + (m << 4) + (kq << 2);
    for (int r = 0; r < 4; ++r) {
      int R = Rbase + r;
      size_t rowoff = (size_t)R * 4096;
      for (int n = 0; n < 4; ++n)
        C[rowoff + (bn << 7) + wc + (n << 4) + r16] = acc[m][n][r] + bvv[n];
    }
  }
}

// ---------------- projection GEMM: logits = hs1rm @ Wout^T + bout ----------------
// 128x128 tiles, both operands via global_load_lds when BF16B (pre-converted Wout).
// Super-tiled order (8 bm x 10 bn per square) for L2/L3 reuse; nt logits stores.
template <bool BF16B>
__global__ __launch_bounds__(256) void gemm_proj(
    const bf16* __restrict__ A, const void* __restrict__ Bw_,
    const float* __restrict__ bias, float* __restrict__ C) {
  __shared__ bf16 aL[2][4096];
  __shared__ bf16 bL[2][4096];
  const int tid = threadIdx.x;
  const int l = tid & 63, w = tid >> 6;
  const int k = blockIdx.x % 80, sq = blockIdx.x / 80;
  const int bm = ((sq & 7) << 3) + (k & 7);    // 0..63
  const int bn = (sq >> 3) * 10 + (k >> 3);    // 0..249
  const int wr = (w >> 1) << 6, wc = (w & 1) << 6;
  const int r16 = l & 15, kq = l >> 4;
  const bf16* Bb = (const bf16*)Bw_;
  const float* Bf32 = (const float*)Bw_;

  f32x4 acc[4][4];
  for (int m = 0; m < 4; ++m)
    for (int n = 0; n < 4; ++n) acc[m][n] = (f32x4){0.f, 0.f, 0.f, 0.f};

  auto stageA = [&](int kt, int buf) {
    for (int i = 0; i < 2; ++i) {
      int lin = tid + (i << 8);
      int r = lin >> 2, s = lin & 3, c = s ^ (r & 3);
      gload_lds16(A + (size_t)((bm << 7) + r) * 1024 + (kt << 5) + (c << 3),
                  &aL[buf][lin << 3]);
    }
  };
  stageA(0, 0);
  if (BF16B) {
    for (int i = 0; i < 2; ++i) {
      int lin = tid + (i << 8);
      int r = lin >> 2, s = lin & 3, c = s ^ (r & 3);
      gload_lds16(Bb + (size_t)((bn << 7) + r) * 1024 + (c << 3), &bL[0][lin << 3]);
    }
  } else {
    for (int i = 0; i < 2; ++i) {
      int lin = tid + (i << 8);
      int r = lin >> 2, c = lin & 3;
      const float* src = Bf32 + (size_t)((bn << 7) + r) * 1024 + (c << 3);
      f32x4 v0 = *(const f32x4*)src;
      f32x4 v1 = *(const f32x4*)(src + 4);
      bf16x8 o;
      for (int j = 0; j < 4; ++j) { o[j] = (bf16)v0[j]; o[j + 4] = (bf16)v1[j]; }
      *(bf16x8*)&bL[0][(r << 5) + ((c ^ (r & 3)) << 3)] = o;
    }
  }
  __syncthreads();

  for (int kt = 0; kt < 32; ++kt) {
    const int cur = kt & 1;
    const bool pf = (kt + 1 < 32);
    f32x4 bv0[2], bv1[2];
    int br_[2], bs_[2];
    if (pf) {
      stageA(kt + 1, cur ^ 1);
      if (BF16B) {
        for (int i = 0; i < 2; ++i) {
          int lin = tid + (i << 8);
          int r = lin >> 2, s = lin & 3, c = s ^ (r & 3);
          gload_lds16(Bb + (size_t)((bn << 7) + r) * 1024 + ((kt + 1) << 5) + (c << 3),
                      &bL[cur ^ 1][lin << 3]);
        }
      } else {
        for (int i = 0; i < 2; ++i) {
          int lin = tid + (i << 8);
          int r = lin >> 2, c = lin & 3;
          const float* src = Bf32 + (size_t)((bn << 7) + r) * 1024 + ((kt + 1) << 5) + (c << 3);
          bv0[i] = *(const f32x4*)src;
          bv1[i] = *(const f32x4*)(src + 4);
          br_[i] = r;
          bs_[i] = c ^ (r & 3);
        }
      }
    }
    bf16x8 af[4], bfr[4];
    for (int m = 0; m < 4; ++m) {
      int row = wr + (m << 4) + r16;
      int ch = kq ^ (row & 3);
      af[m] = *(const bf16x8*)&aL[cur][(row << 5) + (ch << 3)];
    }
    for (int n = 0; n < 4; ++n) {
      int row = wc + (n << 4) + r16;
      int ch = kq ^ (row & 3);
      bfr[n] = *(const bf16x8*)&bL[cur][(row << 5) + (ch << 3)];
    }
    for (int m = 0; m < 4; ++m)
      for (int n = 0; n < 4; ++n)
        acc[m][n] = __builtin_amdgcn_mfma_f32_16x16x32_bf16(af[m], bfr[n], acc[m][n], 0, 0, 0);
    if (pf && !BF16B) {
      for (int i = 0; i < 2; ++i) {
        bf16x8 o;
        for (int j = 0; j < 4; ++j) { o[j] = (bf16)bv0[i][j]; o[j + 4] = (bf16)bv1[i][j]; }
        *(bf16x8*)&bL[cur ^ 1][(br_[i] << 5) + (bs_[i] << 3)] = o;
      }
    }
    __syncthreads();
  }

  float bvv[4];
  for (int n = 0; n < 4; ++n) bvv[n] = bias[(bn << 7) + wc + (n << 4) + r16];
  for (int m = 0; m < 4; ++m) {
    int Rbase = (bm << 7) + wr + (m << 4) + (kq << 2);
    for (int r = 0; r < 4; ++r) {
      int R = Rbase + r;
      int tt = R >> 4, bb = R & 15;
      size_t rowoff = ((size_t)bb * 512 + tt) * 32000;
      for (int n = 0; n < 4; ++n) {
        float v = acc[m][n][r] + bvv[n];
        float* cp = &C[rowoff + (bn << 7) + wc + (n << 4) + r16];
        asm volatile("global_store_dword %0, %1, off nt" ::"v"(cp), "v"(v) : "memory");
      }
    }
  }
}

// ---------------- wave-granular 3-group persistent LSTM pipeline (r7, proven) ----------------
__global__ __launch_bounds__(256, 1) void lstm_pipe3(
    const float* __restrict__ gx,     // [T*16][4096]
    const float* __restrict__ Whh0,   // [4096][1024] f32
    const float* __restrict__ Wih1,   // [4096][1024] f32
    const float* __restrict__ Whh1,   // [4096][1024] f32
    const float* __restrict__ bsum1,  // [4096]
    bf16* __restrict__ hs0t,          // [T][16384] tile format
    bf16* __restrict__ hs1t,          // [T][16384] tile format
    float* __restrict__ gx1,          // ring [8][65536] f32
    bf16* __restrict__ hs1rm,         // [T*16][1024] row-major (projection input)
    unsigned* __restrict__ flags,     // FLAG_WORDS, zeroed
    int T) {
  __shared__ bf16 wlds[4][16 * 1024];
  __shared__ unsigned short hb[4][64];
  __shared__ unsigned tokv[4];
  const int tid = threadIdx.x;
  const int l = tid & 63, w = tid >> 6;
  const int bid = blockIdx.x;
  const int r16 = l & 15, kq = l >> 4;
  unsigned* const fL0 = flags;
  unsigned* const fB = flags + 256;
  unsigned* const fL1 = flags + 512;
  const int typ = bid >> 6;  // 0=L0, 1=B, 2=L1
  const int lb = bid & 63;
  const int widx = lb * 4 + w;
  const int colbase = lb * 16 + w * 4;

  {
    const float* Wsrc = (typ == 0) ? Whh0 : ((typ == 1) ? Wih1 : Whh1);
    for (int it = 0; it < 32; ++it) {
      int lin = it * 64 + l;
      int row = lin >> 7, cs = lin & 127, c = cs ^ (row & 7);
      const float* s = Wsrc + (size_t)((row >> 2) * 1024 + colbase + (row & 3)) * 1024 + c * 8;
      f32x4 v0 = *(const f32x4*)s;
      f32x4 v1 = *(const f32x4*)(s + 4);
      bf16x8 o;
      for (int j = 0; j < 4; ++j) { o[j] = (bf16)v0[j]; o[j + 4] = (bf16)v1[j]; }
      *(bf16x8*)&wlds[w][row * 1024 + cs * 8] = o;
    }
  }
  if (tid < 4) tokv[tid] = 0;
  __syncthreads();

  const int gcol = (r16 >> 2) * 1024 + colbase + (r16 & 3);
  const int b0s = (r16 >> 2) & 1, b1s = (r16 >> 3) & 1;

  auto pollq = [&](unsigned* arr, unsigned tgt) {
    unsigned* q = arr + w * 64 + (l & 15) * 4;
    for (;;) {
      unsigned a0 = __hip_atomic_load(q + 0, __ATOMIC_RELAXED, __HIP_MEMORY_SCOPE_AGENT);
      unsigned a1 = __hip_atomic_load(q + 1, __ATOMIC_RELAXED, __HIP_MEMORY_SCOPE_AGENT);
      unsigned a2 = __hip_atomic_load(q + 2, __ATOMIC_RELAXED, __HIP_MEMORY_SCOPE_AGENT);
      unsigned a3 = __hip_atomic_load(q + 3, __ATOMIC_RELAXED, __HIP_MEMORY_SCOPE_AGENT);
      if (__all(a0 >= tgt && a1 >= tgt && a2 >= tgt && a3 >= tgt)) break;
      __builtin_amdgcn_s_sleep(2);
    }
    volatile unsigned* tk = tokv;
    if (l == 0) tk[w] = tgt;
    while (tk[0] < tgt || tk[1] < tgt || tk[2] < tgt || tk[3] < tgt) {
    }
    asm volatile("" ::: "memory");
  };
  auto poll1 = [&](unsigned* p, unsigned tgt) {
    while (__hip_atomic_load(p, __ATOMIC_RELAXED, __HIP_MEMORY_SCOPE_AGENT) < tgt)
      __builtin_amdgcn_s_sleep(2);
    asm volatile("" ::: "memory");
  };
  auto chain = [&](const bf16* plane) -> f32x4 {
    f32x4 acc = (f32x4){0.f, 0.f, 0.f, 0.f};
    const char* hp = (const char*)plane;
#pragma unroll 8
    for (int kk = 0; kk < 32; ++kk) {
      int tl = kk * 8 + kq * 2;
      unsigned long long lo = *(const unsigned long long*)(hp + tl * 128 + r16 * 8);
      unsigned long long hi = *(const unsigned long long*)(hp + tl * 128 + 128 + r16 * 8);
      union { struct { unsigned long long a, b; } u; bf16x8 v; } A;
      A.u.a = lo;
      A.u.b = hi;
      bf16x8 Bf = *(const bf16x8*)&wlds[w][r16 * 1024 + (((kk * 4 + kq) ^ (r16 & 7)) << 3)];
      acc = __builtin_amdgcn_mfma_f32_16x16x32_bf16(A.v, Bf, acc, 0, 0, 0);
    }
    return acc;
  };

  if (typ == 1) {
    const float bsv = bsum1[gcol];
    unsigned* const myflag = fB + widx;
    unsigned* const partner = fL1 + widx;
    for (int t = 0; t < T; ++t) {
      if (t >= RING) poll1(partner, (unsigned)(t - RING + 1));
      pollq(fL0, (unsigned)(t + 1));
      f32x4 acc = chain(hs0t + (size_t)t * 16384);
      for (int r = 0; r < 4; ++r) acc[r] += bsv;
      float* dst = gx1 + (size_t)(t & (RING - 1)) * 65536 + widx * 256 + r16 * 16 + kq * 4;
      asm volatile("global_store_dwordx4 %0, %1, off sc0 sc1" ::"v"(dst), "v"(acc) : "memory");
      asm volatile("s_waitcnt vmcnt(0)" ::: "memory");
      if (l == 0)
        __hip_atomic_store(myflag, (unsigned)(t + 1), __ATOMIC_RELAXED, __HIP_MEMORY_SCOPE_AGENT);
    }
    return;
  }

  float cst[4] = {0.f, 0.f, 0.f, 0.f};
  unsigned* const myflag = (typ == 0) ? (fL0 + widx) : (fL1 + widx);
  unsigned* const bpartner = fB + widx;
  bf16* const houts = (typ == 0) ? hs0t : hs1t;

  for (int t = 0; t < T; ++t) {
    float gxv[4];
    if (typ == 0) {
      for (int r = 0; r < 4; ++r)
        gxv[r] = gx[(size_t)(t * 16 + kq * 4 + r) * 4096 + gcol];
    }
    if (typ == 0) {
      if (t > 0) pollq(fL0, (unsigned)t);
    } else {
      poll1(bpartner, (unsigned)(t + 1));
      if (t > 0) pollq(fL1, (unsigned)t);
    }
    f32x4 acc = (f32x4){0.f, 0.f, 0.f, 0.f};
    if (t > 0) acc = chain(houts + (size_t)(t - 1) * 16384);
    if (typ == 0) {
      for (int r = 0; r < 4; ++r) acc[r] += gxv[r];
    } else {
      const float* gp = gx1 + (size_t)(t & (RING - 1)) * 65536 + widx * 256 + r16 * 16 + kq * 4;
      f32x4 g1;
      asm volatile("global_load_dwordx4 %0, %1, off sc0 sc1\ns_waitcnt vmcnt(0)"
                   : "=v"(g1) : "v"(gp) : "memory");
      for (int r = 0; r < 4; ++r) acc[r] += g1[r];
    }
    float hv[4];
    for (int r = 0; r < 4; ++r) {
      float own = acc[r];
      float p4 = __shfl_xor(own, 4, 64);
      float ev = b0s ? p4 : own;
      float ov = b0s ? own : p4;
      float ev8 = __shfl_xor(ev, 8, 64);
      float ov8 = __shfl_xor(ov, 8, 64);
      float xi = b1s ? ev8 : ev;
      float xf = b1s ? ov8 : ov;
      float xg = b1s ? ev : ev8;
      float xo = b1s ? ov : ov8;
      float ig = 1.f / (1.f + __expf(-xi));
      float fg = 1.f / (1.f + __expf(-xf));
      float eg = __expf(2.f * xg);
      float gv = 1.f - 2.f / (eg + 1.f);
      float og = 1.f / (1.f + __expf(-xo));
      cst[r] = fg * cst[r] + ig * gv;
      float ec = __expf(2.f * cst[r]);
      float th = 1.f - 2.f / (ec + 1.f);
      hv[r] = og * th;
    }
    if (r16 < 4) {
      volatile unsigned short* hbp = hb[w];
      for (int r = 0; r < 4; ++r) {
        bf16 hbv = (bf16)hv[r];
        hbp[(kq * 4 + r) * 4 + r16] = __builtin_bit_cast(unsigned short, hbv);
      }
    }
    unsigned long long rowv = 0;
    if (l < 16) rowv = *(volatile unsigned long long*)&hb[w][l * 4];
    if (l < 16) {
      char* dst = (char*)houts + (size_t)t * 32768 + widx * 128 + l * 8;
      asm volatile("global_store_dwordx2 %0, %1, off sc0 sc1" ::"v"(dst), "v"(rowv) : "memory");
    }
    asm volatile("s_waitcnt vmcnt(0)" ::: "memory");
    if (l == 0)
      __hip_atomic_store(myflag, (unsigned)(t + 1), __ATOMIC_RELAXED, __HIP_MEMORY_SCOPE_AGENT);
    if (typ == 2 && l < 16) {  // projection mirror: off critical path, plain store
      *(unsigned long long*)((char*)hs1rm + ((size_t)(t * 16 + l) * 1024 + colbase) * 2) = rowv;
    }
  }
}

extern "C" void kernel_launch(void* const* d_in, const int* in_sizes, int n_in,
                              void* d_out, int out_size, void* d_ws, size_t ws_size,
                              hipStream_t stream) {
  const int* x = (const int*)d_in[0];
  const float* emb = (const float*)d_in[1];
  const float* Wih0 = (const float*)d_in[2];
  const float* Whh0 = (const float*)d_in[3];
  const float* bih0 = (const float*)d_in[4];
  const float* bhh0 = (const float*)d_in[5];
  const float* Wih1 = (const float*)d_in[6];
  const float* Whh1 = (const float*)d_in[7];
  const float* bih1 = (const float*)d_in[8];
  const float* bhh1 = (const float*)d_in[9];
  const float* Wout = (const float*)d_in[10];
  const float* bout = (const float*)d_in[11];

  const int T = 512, M = 8192;
  const size_t bfb = (size_t)M * 1024 * 2;         // 16 MiB bf16 plane
  const size_t out_bytes = (size_t)out_size * 4;   // 1.05 GB
  const size_t woutb_bytes = (size_t)32000 * 1024 * 2;  // 65.5 MB

  char* p = (char*)d_ws;
  bf16* hs1rm = (bf16*)p;         p += bfb;
  float* bsum0 = (float*)p;       p += 4096 * 4;
  float* bsum1 = (float*)p;       p += 4096 * 4;
  unsigned* flags = (unsigned*)p; p += FLAG_WORDS * 4;
  size_t base_need = (size_t)(p - (char*)d_ws);
  const bool fat = ws_size >= base_need + woutb_bytes + 256;
  bf16* woutb = (bf16*)p;  // only used when fat

  // d_out scratch (dead until projection writes it):
  float* gx = (float*)d_out;                              // 134 MB @ head
  float* gx1 = (float*)((char*)d_out + (512ull << 20));   // 2 MB ring
  char* tail = (char*)d_out + out_bytes - 2 * bfb;        // 32 MB tail
  bf16* hs0t = (bf16*)tail;
  bf16* hs1t = (bf16*)(tail + bfb);

  init_misc<<<64, 256, 0, stream>>>(bih0, bhh0, bih1, bhh1, bsum0, bsum1, flags);
  if (fat) wout_cvt<<<16000, 256, 0, stream>>>(Wout, woutb);
  gemm_emb<<<64 * 32, 256, 0, stream>>>(x, emb, Wih0, bsum0, gx);
  lstm_pipe3<<<192, 256, 0, stream>>>(gx, Whh0, Wih1, Whh1, bsum1, hs0t, hs1t, gx1, hs1rm,
                                      flags, T);
  if (fat)
    gemm_proj<true><<<16000, 256, 0, stream>>>(hs1rm, woutb, bout, (float*)d_out);
  else
    gemm_proj<false><<<16000, 256, 0, stream>>>(hs1rm, Wout, bout, (float*)d_out);
}